// Round 4
// baseline (50.032 us; speedup 1.0000x reference)
//
#include <hip/hip_runtime.h>
#include <hip/hip_bf16.h>

#define BATCH 64
#define HH 32
#define WW 32
#define CIN 64
#define COUT 64
#define KFEAT 576   // 3*3*64, flattened as ci*9 + kh*3 + kw (ci major)

typedef __bf16 bf16x8 __attribute__((ext_vector_type(8)));
typedef float f32x4 __attribute__((ext_vector_type(4)));

static __device__ __forceinline__ ushort f2bf_bits(float f) {
  __bf16 b = (__bf16)f;
  return __builtin_bit_cast(ushort, b);
}

// One block per output pixel (h,w). 256 threads = 4 waves.
// Per-pixel GEMM: C[64b][64co] = patches[64b][576k] * K[576k][64co], K-permuted
// as k' = p*64 + ci (p = kh*3+kw). Patches staged in LDS (bf16, XOR-swizzled,
// double-buffered, 2 barriers/pixel — the round-1 38.0us structure).
// ROUND-4 DELTA (single change vs round 1): weight loads are NONTEMPORAL.
// The per-XCD weight stream (18.9 MB) was thrashing the 4 MB L2 that holds
// the 9x-reused input slice (3.1 MB); nt marks weight lines evict-first so
// input stays L2-resident and is fetched from HBM ~once.
__global__ __launch_bounds__(256, 4) void LocalConv_kernel(
    const float* __restrict__ in, const float* __restrict__ ker,
    const float* __restrict__ bias, float* __restrict__ out) {
  // A buffers: [2][64 rows][64 ci] bf16, row stride 128B, XOR-swizzled by
  // byte ^= ((row&7)<<4) to kill the stride-128B bank conflict (G4).
  __shared__ __align__(16) ushort Ab[2][64 * 64];

  const int orig = blockIdx.x;
  // XCD-aware swizzle (T1): 1024 blocks, 8 XCDs, 128 contiguous per XCD
  // -> each XCD covers 4 consecutive h rows (input slice ~3.1MB, L2-fits).
  const int hw = (orig & 7) * 128 + (orig >> 3);
  const int h = hw >> 5, w = hw & 31;
  const int tid = threadIdx.x;
  const int lane = tid & 63;
  const int wave = tid >> 6;

  const float* kerhw = ker + (size_t)hw * (KFEAT * COUT);

  float4 st[4];  // in-flight staging regs (issue-early / write-late)

  auto issue = [&](int p) {
    const int hp = h + p / 3 - 1, wp = w + p % 3 - 1;
    const bool ok = ((unsigned)hp < (unsigned)HH) && ((unsigned)wp < (unsigned)WW);
    const float* src = in + ((size_t)hp * WW + wp) * CIN;
#pragma unroll
    for (int i = 0; i < 4; ++i) {
      const int c = i * 256 + tid;       // 0..1023 chunks of float4
      const int brow = c >> 4;           // batch row 0..63
      const int c16 = c & 15;            // float4 index within row
      if (ok) {
        st[i] = *reinterpret_cast<const float4*>(
            src + (size_t)brow * (HH * WW * CIN) + c16 * 4);
      } else {
        st[i] = make_float4(0.f, 0.f, 0.f, 0.f);  // SAME zero padding
      }
    }
  };

  auto writebuf = [&](int p) {
    ushort* buf = &Ab[p & 1][0];
#pragma unroll
    for (int i = 0; i < 4; ++i) {
      const int c = i * 256 + tid;
      const int brow = c >> 4, c16 = c & 15;
      union { ushort us[4]; uint2 u2; } pk;
      pk.us[0] = f2bf_bits(st[i].x);
      pk.us[1] = f2bf_bits(st[i].y);
      pk.us[2] = f2bf_bits(st[i].z);
      pk.us[3] = f2bf_bits(st[i].w);
      const int byteofs = brow * 128 + ((c16 * 8) ^ ((brow & 7) << 4));
      *reinterpret_cast<uint2*>(reinterpret_cast<char*>(buf) + byteofs) = pk.u2;
    }
  };

  f32x4 acc[4];
#pragma unroll
  for (int m = 0; m < 4; ++m) acc[m] = (f32x4){0.f, 0.f, 0.f, 0.f};

  const int co = wave * 16 + (lane & 15);  // this wave's co slice
  const int kgrp = lane >> 4;              // 0..3, k-group within frag

  issue(0);
  writebuf(0);
  __syncthreads();

  for (int p = 0; p < 9; ++p) {
    if (p < 8) issue(p + 1);  // HBM latency hides under compute below

    const ushort* buf = &Ab[p & 1][0];
    // kernel element (ci,co) for pixel p lives at kerhw[ci*576 + p*64 + co]
    const float* kp = kerhw + p * COUT + co;
#pragma unroll
    for (int ks = 0; ks < 2; ++ks) {  // two K=32 steps per pixel
      const int ci0 = ks * 32 + kgrp * 8;
      bf16x8 bfrag;
#pragma unroll
      for (int j = 0; j < 8; ++j)
        bfrag[j] = (__bf16)__builtin_nontemporal_load(
            kp + (size_t)(ci0 + j) * KFEAT);
#pragma unroll
      for (int m = 0; m < 4; ++m) {
        const int row = m * 16 + (lane & 15);
        const int byteofs =
            row * 128 + ((ks * 64 + kgrp * 16) ^ ((row & 7) << 4));
        bf16x8 afrag = *reinterpret_cast<const bf16x8*>(
            reinterpret_cast<const char*>(buf) + byteofs);
        acc[m] = __builtin_amdgcn_mfma_f32_16x16x32_bf16(afrag, bfrag, acc[m],
                                                         0, 0, 0);
      }
    }

    __syncthreads();  // all reads of Ab[p&1] done
    if (p < 8) {
      writebuf(p + 1);  // write Ab[(p+1)&1]
      __syncthreads();  // visible before compute(p+1)
    }
  }

  // Epilogue: C/D layout (16x16x32): col = lane&15, row = (lane>>4)*4 + reg.
  const float bv = bias[hw * COUT + co];
#pragma unroll
  for (int m = 0; m < 4; ++m) {
#pragma unroll
    for (int r = 0; r < 4; ++r) {
      const int b = m * 16 + kgrp * 4 + r;
      out[((size_t)b * (HH * WW) + hw) * COUT + co] = acc[m][r] + bv;
    }
  }
}

extern "C" void kernel_launch(void* const* d_in, const int* in_sizes, int n_in,
                              void* d_out, int out_size, void* d_ws,
                              size_t ws_size, hipStream_t stream) {
  const float* in = (const float*)d_in[0];
  const float* ker = (const float*)d_in[1];
  const float* bias = (const float*)d_in[2];
  float* out = (float*)d_out;
  (void)in_sizes; (void)n_in; (void)out_size; (void)d_ws; (void)ws_size;
  LocalConv_kernel<<<dim3(HH * WW), dim3(256), 0, stream>>>(in, ker, bias, out);
}

// Round 5
// 35.257 us; speedup vs baseline: 1.4191x; 1.4191x over previous
//
#include <hip/hip_runtime.h>
#include <hip/hip_bf16.h>

#define BATCH 64
#define HH 32
#define WW 32
#define CIN 64
#define COUT 64
#define KFEAT 576   // 3*3*64, flattened as ci*9 + kh*3 + kw (ci major)

typedef __bf16 bf16x8 __attribute__((ext_vector_type(8)));
typedef float f32x4 __attribute__((ext_vector_type(4)));

static __device__ __forceinline__ ushort f2bf_bits(float f) {
  __bf16 b = (__bf16)f;
  return __builtin_bit_cast(ushort, b);
}

// One block per output pixel (h,w). 256 threads = 4 waves.
// Per-pixel GEMM: C[64b][64co] = patches[64b][576k] * K[576k][64co], K-permuted
// as k' = p*64 + ci (p = kh*3+kw). Patches staged in LDS (bf16, XOR-swizzled,
// double-buffered, 2 barriers/pixel — the round-1 38.0us structure).
// ROUND-5 DELTA (single change vs round 1): PHASE-ALIGNED pixel ordering.
// At step t, block (h,w) visits the unique neighbor with hp%3==t/3 and
// wp%3==t%3, so ALL 9 readers of any input tile touch it at the SAME step:
// concurrent misses merge, one HBM fetch serves all nine, and the per-XCD
// instantaneous input working set drops 3.1MB -> ~1MB (survives the weight
// stream's L2 churn). Removes the ~70MB input-refetch inferred from R1-R4.
__global__ __launch_bounds__(256, 4) void LocalConv_kernel(
    const float* __restrict__ in, const float* __restrict__ ker,
    const float* __restrict__ bias, float* __restrict__ out) {
  // A buffers: [2][64 rows][64 ci] bf16, row stride 128B, XOR-swizzled by
  // byte ^= ((row&7)<<4) to kill the stride-128B bank conflict (G4).
  __shared__ __align__(16) ushort Ab[2][64 * 64];

  const int orig = blockIdx.x;
  // XCD-aware swizzle (T1): 1024 blocks, 8 XCDs, 128 contiguous per XCD
  // -> each XCD covers 4 consecutive h rows (input slice L2-fits).
  const int hw = (orig & 7) * 128 + (orig >> 3);
  const int h = hw >> 5, w = hw & 31;
  const int hm = h % 3, wm = w % 3;
  const int tid = threadIdx.x;
  const int lane = tid & 63;
  const int wave = tid >> 6;

  const float* kerhw = ker + (size_t)hw * (KFEAT * COUT);

  // Step t -> (hp, wp, p): the unique 3x3-neighbor with hp===t/3, wp===t%3
  // (mod 3). Each block still visits all 9 offsets exactly once.
  auto offs = [&](int t, int& hp, int& wp, int& p) {
    const int t3 = t / 3, t0 = t % 3;
    const int dh = ((t3 + 4 - hm) % 3) - 1;  // (h+dh) % 3 == t3
    const int dw = ((t0 + 4 - wm) % 3) - 1;  // (w+dw) % 3 == t0
    hp = h + dh;
    wp = w + dw;
    p = (dh + 1) * 3 + (dw + 1);
  };

  float4 st[4];  // in-flight staging regs (issue-early / write-late)

  auto issue = [&](int hp, int wp) {
    const bool ok = ((unsigned)hp < (unsigned)HH) && ((unsigned)wp < (unsigned)WW);
    const float* src = in + ((size_t)hp * WW + wp) * CIN;
#pragma unroll
    for (int i = 0; i < 4; ++i) {
      const int c = i * 256 + tid;       // 0..1023 chunks of float4
      const int brow = c >> 4;           // batch row 0..63
      const int c16 = c & 15;            // float4 index within row
      if (ok) {
        st[i] = *reinterpret_cast<const float4*>(
            src + (size_t)brow * (HH * WW * CIN) + c16 * 4);
      } else {
        st[i] = make_float4(0.f, 0.f, 0.f, 0.f);  // SAME zero padding
      }
    }
  };

  auto writebuf = [&](int buf_idx) {
    ushort* buf = &Ab[buf_idx][0];
#pragma unroll
    for (int i = 0; i < 4; ++i) {
      const int c = i * 256 + tid;
      const int brow = c >> 4, c16 = c & 15;
      union { ushort us[4]; uint2 u2; } pk;
      pk.us[0] = f2bf_bits(st[i].x);
      pk.us[1] = f2bf_bits(st[i].y);
      pk.us[2] = f2bf_bits(st[i].z);
      pk.us[3] = f2bf_bits(st[i].w);
      const int byteofs = brow * 128 + ((c16 * 8) ^ ((brow & 7) << 4));
      *reinterpret_cast<uint2*>(reinterpret_cast<char*>(buf) + byteofs) = pk.u2;
    }
  };

  f32x4 acc[4];
#pragma unroll
  for (int m = 0; m < 4; ++m) acc[m] = (f32x4){0.f, 0.f, 0.f, 0.f};

  const int co = wave * 16 + (lane & 15);  // this wave's co slice
  const int kgrp = lane >> 4;              // 0..3, k-group within frag

  int hp, wp, p;
  offs(0, hp, wp, p);
  issue(hp, wp);
  writebuf(0);
  __syncthreads();

  for (int t = 0; t < 9; ++t) {
    int pcur = p;  // weight pixel index for this step
    if (t < 8) {
      offs(t + 1, hp, wp, p);
      issue(hp, wp);  // HBM latency hides under compute below
    }

    const ushort* buf = &Ab[t & 1][0];
    // kernel element (ci,co) for pixel pcur lives at kerhw[ci*576 + pcur*64 + co]
    const float* kp = kerhw + pcur * COUT + co;
#pragma unroll
    for (int ks = 0; ks < 2; ++ks) {  // two K=32 steps per pixel
      const int ci0 = ks * 32 + kgrp * 8;
      bf16x8 bfrag;
#pragma unroll
      for (int j = 0; j < 8; ++j)
        bfrag[j] = (__bf16)kp[(size_t)(ci0 + j) * KFEAT];
#pragma unroll
      for (int m = 0; m < 4; ++m) {
        const int row = m * 16 + (lane & 15);
        const int byteofs =
            row * 128 + ((ks * 64 + kgrp * 16) ^ ((row & 7) << 4));
        bf16x8 afrag = *reinterpret_cast<const bf16x8*>(
            reinterpret_cast<const char*>(buf) + byteofs);
        acc[m] = __builtin_amdgcn_mfma_f32_16x16x32_bf16(afrag, bfrag, acc[m],
                                                         0, 0, 0);
      }
    }

    __syncthreads();  // all reads of Ab[t&1] done
    if (t < 8) {
      writebuf((t + 1) & 1);  // write Ab[(t+1)&1]
      __syncthreads();        // visible before compute(t+1)
    }
  }

  // Epilogue: C/D layout (16x16x32): col = lane&15, row = (lane>>4)*4 + reg.
  const float bv = bias[hw * COUT + co];
#pragma unroll
  for (int m = 0; m < 4; ++m) {
#pragma unroll
    for (int r = 0; r < 4; ++r) {
      const int b = m * 16 + kgrp * 4 + r;
      out[((size_t)b * (HH * WW) + hw) * COUT + co] = acc[m][r] + bv;
    }
  }
}

extern "C" void kernel_launch(void* const* d_in, const int* in_sizes, int n_in,
                              void* d_out, int out_size, void* d_ws,
                              size_t ws_size, hipStream_t stream) {
  const float* in = (const float*)d_in[0];
  const float* ker = (const float*)d_in[1];
  const float* bias = (const float*)d_in[2];
  float* out = (float*)d_out;
  (void)in_sizes; (void)n_in; (void)out_size; (void)d_ws; (void)ws_size;
  LocalConv_kernel<<<dim3(HH * WW), dim3(256), 0, stream>>>(in, ker, bias, out);
}